// Round 7
// baseline (502.613 us; speedup 1.0000x reference)
//
#include <hip/hip_runtime.h>

#define NNODES 4096
#define NCH    128
#define NE     10

// ---------------- workspace layout (float elements) ----------------
// [0..16)    counts (int)
// [16..32)   cursor (int)
// [48..4144) list (int, q -> b)
// 4160:      T3ws [e][c][6561]   (8,398,080)   (dij-major, n fastest)
// then       T2ws [e][c][729]    (933,120)
// then       T1ws [e][c][81]     (103,680)
// then       pre  [c][D][q]      (4,718,592)
// then       xg   [c][n][q]      (4,718,592)
// total ~75.5 MB

// ---------------- bucketing ----------------
__global__ void k_count(const float* __restrict__ attrs, int* __restrict__ counts)
{
    int b = blockIdx.x * 256 + threadIdx.x;
    if (b >= NNODES) return;
    const float* y = attrs + (size_t)b * NE;
    int e = 0;
#pragma unroll
    for (int t = 0; t < NE; ++t) if (y[t] > 0.5f) e = t;
    atomicAdd(&counts[e], 1);
}

__global__ void k_scatter(const float* __restrict__ attrs, const int* __restrict__ counts,
                          int* __restrict__ cursor, int* __restrict__ list)
{
    int b = blockIdx.x * 256 + threadIdx.x;
    if (b >= NNODES) return;
    const float* y = attrs + (size_t)b * NE;
    int e = 0;
#pragma unroll
    for (int t = 0; t < NE; ++t) if (y[t] > 0.5f) e = t;
    int off = 0;
#pragma unroll
    for (int u = 0; u < NE; ++u) off += (u < e) ? counts[u] : 0;
    int pos = atomicAdd(&cursor[e], 1);
    list[off + pos] = b;
}

// ---------------- fused gather + table precompute ----------------
// blocks [0,512): gather-transpose   (needs list)
// blocks [512,2572): T3   [2572,6217): T2   [6217,6622): T1   (independent)
__global__ __launch_bounds__(256) void k_gp(
    const float* __restrict__ nf, const int* __restrict__ list,
    const float* __restrict__ U3_0, const float* __restrict__ U3_1, const float* __restrict__ U3_2,
    const float* __restrict__ W3_0, const float* __restrict__ W3_1, const float* __restrict__ W3_2,
    const float* __restrict__ U2_0, const float* __restrict__ U2_1, const float* __restrict__ U2_2,
    const float* __restrict__ W2_0, const float* __restrict__ W2_1, const float* __restrict__ W2_2,
    const float* __restrict__ U1_0, const float* __restrict__ U1_1, const float* __restrict__ U1_2,
    const float* __restrict__ W1_0, const float* __restrict__ W1_1, const float* __restrict__ W1_2,
    float* __restrict__ xg, float* __restrict__ T3ws, float* __restrict__ T2ws,
    float* __restrict__ T1ws)
{
    __shared__ __align__(16) float smem[64 * 145];
    __shared__ int lb[64];
    int bid = blockIdx.x, t = threadIdx.x;
    if (bid < 512) {
        // ---- gather-transpose: xg[(c*9+n)*4096+q] = nf[(list[q]*128+c)*9+n] ----
        int qb = bid >> 3, ct = bid & 7;
        int c0 = ct * 16;
        if (t < 64) lb[t] = list[qb * 64 + t];
        __syncthreads();
#pragma unroll 1
        for (int k = 0; k < 36; ++k) {
            int idx = k * 256 + t;                // 64 nodes * 144 elems
            int node = idx / 144, elem = idx - node * 144;
            smem[node * 145 + elem] = nf[((size_t)lb[node] * 128 + c0) * 9 + elem];
        }
        __syncthreads();
#pragma unroll 1
        for (int k = 0; k < 36; ++k) {
            int idx = k * 256 + t;
            int node = idx & 63, re = idx >> 6;
            xg[((size_t)(c0 * 9 + re)) * NNODES + qb * 64 + node] = smem[node * 145 + re];
        }
    } else if (bid < 2572) {
        // ---- T3: per (e, 32-row chunk), LDS transpose, coalesced out ----
        int bid2 = bid - 512;
        int e = bid2 / 206, cid = bid2 - e * 206;
        const float* U3; const float* W3; int chunk0, rows, Dbase;
        if (cid < 23)      { chunk0 = cid;      rows = 729;  U3 = U3_0; W3 = W3_0; Dbase = 0; }
        else if (cid < 92) { chunk0 = cid - 23; rows = 2187; U3 = U3_1; W3 = W3_1; Dbase = 1; }
        else               { chunk0 = cid - 92; rows = 3645; U3 = U3_2; W3 = W3_2; Dbase = 4; }
        int c = t & 127, sub = t >> 7;
        float w[30];
#pragma unroll
        for (int k = 0; k < 30; ++k) w[k] = W3[((size_t)e * 30 + k) * 128 + c];
        float* tile = smem;                       // 32*129 = 4128 floats
        int row0 = chunk0 * 32;
#pragma unroll 1
        for (int rr = sub * 16; rr < sub * 16 + 16; ++rr) {
            int row = row0 + rr;
            float val = 0.0f;
            if (row < rows) {
                const float2* u2 = (const float2*)(U3 + (size_t)row * 30);
#pragma unroll
                for (int kk = 0; kk < 15; ++kk) {
                    float2 uv = u2[kk];
                    val = fmaf(uv.x, w[2 * kk], val);
                    val = fmaf(uv.y, w[2 * kk + 1], val);
                }
            }
            tile[rr * 129 + c] = val;
        }
        __syncthreads();
#pragma unroll 1
        for (int wv = 0; wv < 16; ++wv) {
            int idx = t + 256 * wv;
            int cc = idx >> 5, rr = idx & 31;
            int row = row0 + rr;
            if (row < rows)
                T3ws[((size_t)e * 128 + cc) * 6561 + (size_t)(Dbase * 729 + row)] = tile[rr * 129 + cc];
        }
    } else if (bid < 6217) {
        // ---- T2 (coalesced, dij-major per (e,c)) ----
        int idx = (bid - 2572) * 256 + t;         // 933120 exact
        int dij = idx % 729;
        int c = (idx / 729) & 127;
        int e = idx / (729 * 128);
        int D = dij / 81, ij = dij - D * 81;
        const float* U2; const float* W2; int dloc;
        if (D == 0)      { U2 = U2_0; W2 = W2_0; dloc = 0; }
        else if (D < 4)  { U2 = U2_1; W2 = W2_1; dloc = D - 1; }
        else             { U2 = U2_2; W2 = W2_2; dloc = D - 4; }
        float val = 0.0f;
#pragma unroll
        for (int k = 0; k < 12; ++k)
            val = fmaf(U2[(size_t)(dloc * 81 + ij) * 12 + k], W2[((size_t)e * 12 + k) * 128 + c], val);
        T2ws[idx] = val;
    } else {
        // ---- T1 (coalesced) ----
        int idx = (bid - 6217) * 256 + t;         // 103680 exact
        int di = idx % 81;
        int c = (idx / 81) & 127;
        int e = idx / (81 * 128);
        int D = di / 9, i = di - D * 9;
        const float* U1; const float* W1; int dloc;
        if (D == 0)      { U1 = U1_0; W1 = W1_0; dloc = 0; }
        else if (D < 4)  { U1 = U1_1; W1 = W1_1; dloc = D - 1; }
        else             { U1 = U1_2; W1 = W1_2; dloc = D - 4; }
        float val = 0.0f;
#pragma unroll
        for (int k = 0; k < 4; ++k)
            val = fmaf(U1[(size_t)(dloc * 9 + i) * 4 + k], W1[((size_t)e * 4 + k) * 128 + c], val);
        T1ws[idx] = val;
    }
}

// ---------------- main contraction ----------------
// 2-wave blocks, NB=1: wave w covers nodes [cb0 + 64w, +64) of one (e,c).
// Tables via wave-uniform scalar loads; no LDS; VGPR ~30 -> 8 waves/SIMD.
// grid (128 c, 10 e, 4 z) = 5120 blocks = 10240 waves ~ 40/CU.
__global__ __launch_bounds__(128, 8) void k_main(
    const float* __restrict__ xg, const int* __restrict__ counts,
    const float* __restrict__ T3ws, const float* __restrict__ T2ws,
    const float* __restrict__ T1ws, float* __restrict__ pre)
{
    int c = blockIdx.x, e = blockIdx.y, z = blockIdx.z;
    int wave = threadIdx.x >> 6, lane = threadIdx.x & 63;
    int cnt = counts[e];
    int qstart = 0;
#pragma unroll
    for (int u = 0; u < NE; ++u) qstart += (u < e) ? counts[u] : 0;
    const float* t3 = T3ws + ((size_t)e * NCH + c) * 6561;
    const float* t2 = T2ws + ((size_t)e * NCH + c) * 729;
    const float* t1 = T1ws + ((size_t)e * NCH + c) * 81;
    const float* xq = xg + (size_t)c * 9 * NNODES + qstart;
    float* preq = pre + (size_t)c * 9 * NNODES + qstart;

#pragma unroll 1
    for (int cb0 = z * 128; cb0 < cnt; cb0 += 512) {
        int cb = cb0 + wave * 64;
        if (cb >= cnt) continue;                 // wave-uniform early exit
        int pos = cb + lane;
        bool v = pos < cnt;
        int p = v ? pos : 0;
        float x[9];
#pragma unroll
        for (int n = 0; n < 9; ++n)
            x[n] = v ? xq[(size_t)n * NNODES + p] : 0.0f;
#pragma unroll 1
        for (int D = 0; D < 9; ++D) {
            float acc3 = 0.0f;
#pragma unroll 1
            for (int i = 0; i < 9; ++i) {
                const float* r3 = t3 + (size_t)(D * 81 + i * 9) * 9;   // 81 contiguous
                const float* r2 = t2 + (size_t)(D * 81 + i * 9);       // 9 contiguous
                float acc2 = t1[D * 9 + i];
#pragma unroll
                for (int j = 0; j < 9; ++j) {
                    const float* r = r3 + j * 9;
                    float acc1 = r2[j];
                    acc1 = fmaf(r[0], x[0], acc1);
                    acc1 = fmaf(r[1], x[1], acc1);
                    acc1 = fmaf(r[2], x[2], acc1);
                    acc1 = fmaf(r[3], x[3], acc1);
                    acc1 = fmaf(r[4], x[4], acc1);
                    acc1 = fmaf(r[5], x[5], acc1);
                    acc1 = fmaf(r[6], x[6], acc1);
                    acc1 = fmaf(r[7], x[7], acc1);
                    acc1 = fmaf(r[8], x[8], acc1);
                    acc2 = fmaf(acc1, x[j], acc2);
                }
                acc3 = fmaf(acc2, x[i], acc3);
            }
            if (v) preq[(size_t)D * NNODES + pos] = acc3;
        }
    }
}

// ---------------- channel mix + permute + sc add (fused epilogue) ----------------
// grid (64 qb, 9 D), block 256 = (16 tq x 16 tf); thread: 4 q x 8 f.
__global__ __launch_bounds__(256) void k_mixout(
    const float* __restrict__ pre, const int* __restrict__ list,
    const float* __restrict__ sc,
    const float* __restrict__ lin0, const float* __restrict__ lin1,
    const float* __restrict__ lin2, float* __restrict__ out)
{
    int qb = blockIdx.x, D = blockIdx.y;
    int t = threadIdx.x;
    int tq = t & 15, tf = t >> 4;
    int q0 = qb * 64 + tq * 4;
    int f0 = tf * 8;
    const float* lin; int L, dl;
    if (D == 0)      { lin = lin0; L = 0; dl = 0; }
    else if (D < 4)  { lin = lin1; L = 1; dl = D - 1; }
    else             { lin = lin2; L = 2; dl = D - 4; }

    float acc[4][8];
#pragma unroll
    for (int qi = 0; qi < 4; ++qi)
#pragma unroll
        for (int ff = 0; ff < 8; ++ff) acc[qi][ff] = 0.0f;

#pragma unroll 2
    for (int c = 0; c < 128; ++c) {
        float4 pv = *(const float4*)&pre[((size_t)c * 9 + D) * NNODES + q0];
        float4 la = *(const float4*)&lin[c * 128 + f0];
        float4 lb = *(const float4*)&lin[c * 128 + f0 + 4];
        float l[8] = {la.x, la.y, la.z, la.w, lb.x, lb.y, lb.z, lb.w};
        float p[4] = {pv.x, pv.y, pv.z, pv.w};
#pragma unroll
        for (int qi = 0; qi < 4; ++qi)
#pragma unroll
            for (int ff = 0; ff < 8; ++ff)
                acc[qi][ff] = fmaf(p[qi], l[ff], acc[qi][ff]);
    }

    const float nrm = 0.08838834764831845f;   // 1/sqrt(128)
#pragma unroll
    for (int qi = 0; qi < 4; ++qi) {
        int b = list[q0 + qi];
        float* ob = out + (size_t)b * 1152;
        const float* scb = sc + (size_t)b * 1152;
        if (L == 0) {
#pragma unroll
            for (int ff = 0; ff < 8; ++ff)
                ob[f0 + ff] = fmaf(nrm, acc[qi][ff], scb[f0 + ff]);
        } else if (L == 1) {
#pragma unroll
            for (int ff = 0; ff < 8; ++ff) {
                int col = 128 + (f0 + ff) * 3 + dl;
                ob[col] = fmaf(nrm, acc[qi][ff], scb[col]);
            }
        } else {
#pragma unroll
            for (int ff = 0; ff < 8; ++ff) {
                int col = 512 + (f0 + ff) * 5 + dl;
                ob[col] = fmaf(nrm, acc[qi][ff], scb[col]);
            }
        }
    }
}

// ---------------- launch ----------------
extern "C" void kernel_launch(void* const* d_in, const int* in_sizes, int n_in,
                              void* d_out, int out_size, void* d_ws, size_t ws_size,
                              hipStream_t stream)
{
    const float* nf    = (const float*)d_in[0];
    const float* sc    = (const float*)d_in[1];
    const float* attrs = (const float*)d_in[2];
    const float *U3s[3], *U2s[3], *U1s[3], *W3s[3], *W2s[3], *W1s[3], *lins[3];
    for (int L = 0; L < 3; ++L) {
        const int o = 3 + 7 * L;
        U3s[L]  = (const float*)d_in[o + 0];
        U2s[L]  = (const float*)d_in[o + 1];
        U1s[L]  = (const float*)d_in[o + 2];
        W3s[L]  = (const float*)d_in[o + 3];
        W2s[L]  = (const float*)d_in[o + 4];
        W1s[L]  = (const float*)d_in[o + 5];
        lins[L] = (const float*)d_in[o + 6];
    }

    float* wsf   = (float*)d_ws;
    int* counts  = (int*)d_ws;
    int* cursor  = counts + 16;
    int* list    = counts + 48;
    float* T3ws = wsf + 4160;
    float* T2ws = T3ws + 8398080;
    float* T1ws = T2ws + 933120;
    float* pre  = T1ws + 103680;
    float* xg   = pre + 4718592;

    hipMemsetAsync(d_ws, 0, 128, stream);   // counts + cursor
    k_count  <<<16, 256, 0, stream>>>(attrs, counts);
    k_scatter<<<16, 256, 0, stream>>>(attrs, counts, cursor, list);
    k_gp<<<6622, 256, 0, stream>>>(nf, list,
                                   U3s[0], U3s[1], U3s[2], W3s[0], W3s[1], W3s[2],
                                   U2s[0], U2s[1], U2s[2], W2s[0], W2s[1], W2s[2],
                                   U1s[0], U1s[1], U1s[2], W1s[0], W1s[1], W1s[2],
                                   xg, T3ws, T2ws, T1ws);
    k_main<<<dim3(128, 10, 4), 128, 0, stream>>>(xg, counts, T3ws, T2ws, T1ws, pre);
    k_mixout<<<dim3(64, 9), 256, 0, stream>>>(pre, list, sc, lins[0], lins[1], lins[2], (float*)d_out);
}

// Round 8
// 368.829 us; speedup vs baseline: 1.3627x; 1.3627x over previous
//
#include <hip/hip_runtime.h>

#define NNODES 4096
#define NCH    128
#define NE     10

// ---------------- workspace layout (float elements) ----------------
// [0..16)    counts (int)
// [16..32)   cursor (int)
// [48..4144) list (int, q -> b)
// 4160:      T3ws [e][c][6561]   (8,398,080)   (dij-major, n fastest)
// then       T2ws [e][c][729]    (933,120)
// then       T1ws [e][c][81]     (103,680)
// then       pre  [c][D][q]      (4,718,592)
// then       xg   [c][n][q]      (4,718,592)
// total ~75.5 MB

// ---------------- bucketing ----------------
__global__ void k_count(const float* __restrict__ attrs, int* __restrict__ counts)
{
    int b = blockIdx.x * 256 + threadIdx.x;
    if (b >= NNODES) return;
    const float* y = attrs + (size_t)b * NE;
    int e = 0;
#pragma unroll
    for (int t = 0; t < NE; ++t) if (y[t] > 0.5f) e = t;
    atomicAdd(&counts[e], 1);
}

__global__ void k_scatter(const float* __restrict__ attrs, const int* __restrict__ counts,
                          int* __restrict__ cursor, int* __restrict__ list)
{
    int b = blockIdx.x * 256 + threadIdx.x;
    if (b >= NNODES) return;
    const float* y = attrs + (size_t)b * NE;
    int e = 0;
#pragma unroll
    for (int t = 0; t < NE; ++t) if (y[t] > 0.5f) e = t;
    int off = 0;
#pragma unroll
    for (int u = 0; u < NE; ++u) off += (u < e) ? counts[u] : 0;
    int pos = atomicAdd(&cursor[e], 1);
    list[off + pos] = b;
}

// ---------------- fused gather + table precompute ----------------
// blocks [0,512): gather-transpose   (needs list)
// blocks [512,2572): T3   [2572,6217): T2   [6217,6622): T1   (independent)
__global__ __launch_bounds__(256) void k_gp(
    const float* __restrict__ nf, const int* __restrict__ list,
    const float* __restrict__ U3_0, const float* __restrict__ U3_1, const float* __restrict__ U3_2,
    const float* __restrict__ W3_0, const float* __restrict__ W3_1, const float* __restrict__ W3_2,
    const float* __restrict__ U2_0, const float* __restrict__ U2_1, const float* __restrict__ U2_2,
    const float* __restrict__ W2_0, const float* __restrict__ W2_1, const float* __restrict__ W2_2,
    const float* __restrict__ U1_0, const float* __restrict__ U1_1, const float* __restrict__ U1_2,
    const float* __restrict__ W1_0, const float* __restrict__ W1_1, const float* __restrict__ W1_2,
    float* __restrict__ xg, float* __restrict__ T3ws, float* __restrict__ T2ws,
    float* __restrict__ T1ws)
{
    __shared__ __align__(16) float smem[64 * 145];
    __shared__ int lb[64];
    int bid = blockIdx.x, t = threadIdx.x;
    if (bid < 512) {
        // ---- gather-transpose: xg[(c*9+n)*4096+q] = nf[(list[q]*128+c)*9+n] ----
        int qb = bid >> 3, ct = bid & 7;
        int c0 = ct * 16;
        if (t < 64) lb[t] = list[qb * 64 + t];
        __syncthreads();
#pragma unroll 1
        for (int k = 0; k < 36; ++k) {
            int idx = k * 256 + t;                // 64 nodes * 144 elems
            int node = idx / 144, elem = idx - node * 144;
            smem[node * 145 + elem] = nf[((size_t)lb[node] * 128 + c0) * 9 + elem];
        }
        __syncthreads();
#pragma unroll 1
        for (int k = 0; k < 36; ++k) {
            int idx = k * 256 + t;
            int node = idx & 63, re = idx >> 6;
            xg[((size_t)(c0 * 9 + re)) * NNODES + qb * 64 + node] = smem[node * 145 + re];
        }
    } else if (bid < 2572) {
        // ---- T3: per (e, 32-row chunk), LDS transpose, coalesced out ----
        int bid2 = bid - 512;
        int e = bid2 / 206, cid = bid2 - e * 206;
        const float* U3; const float* W3; int chunk0, rows, Dbase;
        if (cid < 23)      { chunk0 = cid;      rows = 729;  U3 = U3_0; W3 = W3_0; Dbase = 0; }
        else if (cid < 92) { chunk0 = cid - 23; rows = 2187; U3 = U3_1; W3 = W3_1; Dbase = 1; }
        else               { chunk0 = cid - 92; rows = 3645; U3 = U3_2; W3 = W3_2; Dbase = 4; }
        int c = t & 127, sub = t >> 7;
        float w[30];
#pragma unroll
        for (int k = 0; k < 30; ++k) w[k] = W3[((size_t)e * 30 + k) * 128 + c];
        float* tile = smem;                       // 32*129 = 4128 floats
        int row0 = chunk0 * 32;
#pragma unroll 1
        for (int rr = sub * 16; rr < sub * 16 + 16; ++rr) {
            int row = row0 + rr;
            float val = 0.0f;
            if (row < rows) {
                const float2* u2 = (const float2*)(U3 + (size_t)row * 30);
#pragma unroll
                for (int kk = 0; kk < 15; ++kk) {
                    float2 uv = u2[kk];
                    val = fmaf(uv.x, w[2 * kk], val);
                    val = fmaf(uv.y, w[2 * kk + 1], val);
                }
            }
            tile[rr * 129 + c] = val;
        }
        __syncthreads();
#pragma unroll 1
        for (int wv = 0; wv < 16; ++wv) {
            int idx = t + 256 * wv;
            int cc = idx >> 5, rr = idx & 31;
            int row = row0 + rr;
            if (row < rows)
                T3ws[((size_t)e * 128 + cc) * 6561 + (size_t)(Dbase * 729 + row)] = tile[rr * 129 + cc];
        }
    } else if (bid < 6217) {
        // ---- T2 (coalesced, dij-major per (e,c)) ----
        int idx = (bid - 2572) * 256 + t;         // 933120 exact
        int dij = idx % 729;
        int c = (idx / 729) & 127;
        int e = idx / (729 * 128);
        int D = dij / 81, ij = dij - D * 81;
        const float* U2; const float* W2; int dloc;
        if (D == 0)      { U2 = U2_0; W2 = W2_0; dloc = 0; }
        else if (D < 4)  { U2 = U2_1; W2 = W2_1; dloc = D - 1; }
        else             { U2 = U2_2; W2 = W2_2; dloc = D - 4; }
        float val = 0.0f;
#pragma unroll
        for (int k = 0; k < 12; ++k)
            val = fmaf(U2[(size_t)(dloc * 81 + ij) * 12 + k], W2[((size_t)e * 12 + k) * 128 + c], val);
        T2ws[idx] = val;
    } else {
        // ---- T1 (coalesced) ----
        int idx = (bid - 6217) * 256 + t;         // 103680 exact
        int di = idx % 81;
        int c = (idx / 81) & 127;
        int e = idx / (81 * 128);
        int D = di / 9, i = di - D * 9;
        const float* U1; const float* W1; int dloc;
        if (D == 0)      { U1 = U1_0; W1 = W1_0; dloc = 0; }
        else if (D < 4)  { U1 = U1_1; W1 = W1_1; dloc = D - 1; }
        else             { U1 = U1_2; W1 = W1_2; dloc = D - 4; }
        float val = 0.0f;
#pragma unroll
        for (int k = 0; k < 4; ++k)
            val = fmaf(U1[(size_t)(dloc * 9 + i) * 4 + k], W1[((size_t)e * 4 + k) * 128 + c], val);
        T1ws[idx] = val;
    }
}

// ---------------- main contraction ----------------
// NB node-chunks per wave (independent FMA chains), 3 D per wave.
// Tables via wave-uniform scalar loads, amortized over NB chunks. No LDS.
template <int NB>
__device__ __forceinline__ void eq_chunk(
    const float* __restrict__ xq, const float* __restrict__ t3,
    const float* __restrict__ t2, const float* __restrict__ t1,
    float* __restrict__ preq, int cb, int cnt, int lane, int dbase)
{
    float x[NB][9];
#pragma unroll
    for (int t = 0; t < NB; ++t) {
        int pos = cb + t * 64 + lane;
        bool v = pos < cnt;
        int p = v ? pos : 0;
#pragma unroll
        for (int n = 0; n < 9; ++n)
            x[t][n] = v ? xq[(size_t)n * NNODES + p] : 0.0f;
    }
#pragma unroll 1
    for (int dd = 0; dd < 3; ++dd) {
        int D = dbase + dd;
        float acc3[NB];
#pragma unroll
        for (int t = 0; t < NB; ++t) acc3[t] = 0.0f;
#pragma unroll 1
        for (int i = 0; i < 9; ++i) {
            const float* r3 = t3 + (size_t)(D * 81 + i * 9) * 9;   // 81 contiguous floats
            const float* r2 = t2 + (size_t)(D * 81 + i * 9);       // 9 contiguous
            float t1v = t1[D * 9 + i];
            float acc2[NB];
#pragma unroll
            for (int t = 0; t < NB; ++t) acc2[t] = t1v;
#pragma unroll
            for (int j = 0; j < 9; ++j) {
                const float* r = r3 + j * 9;
                float t2v = r2[j];
                float acc1[NB];
#pragma unroll
                for (int t = 0; t < NB; ++t) acc1[t] = t2v;
#pragma unroll
                for (int t = 0; t < NB; ++t) {
                    acc1[t] = fmaf(r[0], x[t][0], acc1[t]);
                    acc1[t] = fmaf(r[1], x[t][1], acc1[t]);
                    acc1[t] = fmaf(r[2], x[t][2], acc1[t]);
                    acc1[t] = fmaf(r[3], x[t][3], acc1[t]);
                    acc1[t] = fmaf(r[4], x[t][4], acc1[t]);
                    acc1[t] = fmaf(r[5], x[t][5], acc1[t]);
                    acc1[t] = fmaf(r[6], x[t][6], acc1[t]);
                    acc1[t] = fmaf(r[7], x[t][7], acc1[t]);
                    acc1[t] = fmaf(r[8], x[t][8], acc1[t]);
                    acc2[t] = fmaf(acc1[t], x[t][j], acc2[t]);
                }
            }
#pragma unroll
            for (int t = 0; t < NB; ++t) acc3[t] = fmaf(acc2[t], x[t][i], acc3[t]);
        }
#pragma unroll
        for (int t = 0; t < NB; ++t) {
            int pos = cb + t * 64 + lane;
            if (pos < cnt)
                preq[(size_t)D * NNODES + pos] = acc3[t];
        }
    }
}

// grid (128 c, 10 e, 6 zd): zd = (znode in [0,2)) | (dgrp in [0,3)) -> 7680 waves ~30/CU.
// Each wave: 256-node chunk (NB=4) at znode*256, D in [dgrp*3, +3).
// VGPR ~60 -> 6 waves/SIMD under __launch_bounds__(64,6).
__global__ __launch_bounds__(64, 6) void k_main(
    const float* __restrict__ xg, const int* __restrict__ counts,
    const float* __restrict__ T3ws, const float* __restrict__ T2ws,
    const float* __restrict__ T1ws, float* __restrict__ pre)
{
    int c = blockIdx.x, e = blockIdx.y, zd = blockIdx.z;
    int znode = zd & 1, dbase = (zd >> 1) * 3;
    int lane = threadIdx.x;
    int cnt = counts[e];
    int qstart = 0;
#pragma unroll
    for (int u = 0; u < NE; ++u) qstart += (u < e) ? counts[u] : 0;
    const float* t3 = T3ws + ((size_t)e * NCH + c) * 6561;
    const float* t2 = T2ws + ((size_t)e * NCH + c) * 729;
    const float* t1 = T1ws + ((size_t)e * NCH + c) * 81;
    const float* xq = xg + (size_t)c * 9 * NNODES + qstart;
    float* preq = pre + (size_t)c * 9 * NNODES + qstart;

#pragma unroll 1
    for (int cb = znode * 256; cb < cnt; cb += 512) {
        int rem = cnt - cb;
        int nb = (rem + 63) >> 6;
        if (nb >= 4) {
            eq_chunk<4>(xq, t3, t2, t1, preq, cb, cnt, lane, dbase);
        } else if (nb == 3) {
            eq_chunk<3>(xq, t3, t2, t1, preq, cb, cnt, lane, dbase);
        } else if (nb == 2) {
            eq_chunk<2>(xq, t3, t2, t1, preq, cb, cnt, lane, dbase);
        } else {
            eq_chunk<1>(xq, t3, t2, t1, preq, cb, cnt, lane, dbase);
        }
    }
}

// ---------------- channel mix + permute + sc add (fused epilogue) ----------------
// grid (64 qb, 9 D), block 256 = (16 tq x 16 tf); thread: 4 q x 8 f.
__global__ __launch_bounds__(256) void k_mixout(
    const float* __restrict__ pre, const int* __restrict__ list,
    const float* __restrict__ sc,
    const float* __restrict__ lin0, const float* __restrict__ lin1,
    const float* __restrict__ lin2, float* __restrict__ out)
{
    int qb = blockIdx.x, D = blockIdx.y;
    int t = threadIdx.x;
    int tq = t & 15, tf = t >> 4;
    int q0 = qb * 64 + tq * 4;
    int f0 = tf * 8;
    const float* lin; int L, dl;
    if (D == 0)      { lin = lin0; L = 0; dl = 0; }
    else if (D < 4)  { lin = lin1; L = 1; dl = D - 1; }
    else             { lin = lin2; L = 2; dl = D - 4; }

    float acc[4][8];
#pragma unroll
    for (int qi = 0; qi < 4; ++qi)
#pragma unroll
        for (int ff = 0; ff < 8; ++ff) acc[qi][ff] = 0.0f;

#pragma unroll 2
    for (int c = 0; c < 128; ++c) {
        float4 pv = *(const float4*)&pre[((size_t)c * 9 + D) * NNODES + q0];
        float4 la = *(const float4*)&lin[c * 128 + f0];
        float4 lb = *(const float4*)&lin[c * 128 + f0 + 4];
        float l[8] = {la.x, la.y, la.z, la.w, lb.x, lb.y, lb.z, lb.w};
        float p[4] = {pv.x, pv.y, pv.z, pv.w};
#pragma unroll
        for (int qi = 0; qi < 4; ++qi)
#pragma unroll
            for (int ff = 0; ff < 8; ++ff)
                acc[qi][ff] = fmaf(p[qi], l[ff], acc[qi][ff]);
    }

    const float nrm = 0.08838834764831845f;   // 1/sqrt(128)
#pragma unroll
    for (int qi = 0; qi < 4; ++qi) {
        int b = list[q0 + qi];
        float* ob = out + (size_t)b * 1152;
        const float* scb = sc + (size_t)b * 1152;
        if (L == 0) {
#pragma unroll
            for (int ff = 0; ff < 8; ++ff)
                ob[f0 + ff] = fmaf(nrm, acc[qi][ff], scb[f0 + ff]);
        } else if (L == 1) {
#pragma unroll
            for (int ff = 0; ff < 8; ++ff) {
                int col = 128 + (f0 + ff) * 3 + dl;
                ob[col] = fmaf(nrm, acc[qi][ff], scb[col]);
            }
        } else {
#pragma unroll
            for (int ff = 0; ff < 8; ++ff) {
                int col = 512 + (f0 + ff) * 5 + dl;
                ob[col] = fmaf(nrm, acc[qi][ff], scb[col]);
            }
        }
    }
}

// ---------------- launch ----------------
extern "C" void kernel_launch(void* const* d_in, const int* in_sizes, int n_in,
                              void* d_out, int out_size, void* d_ws, size_t ws_size,
                              hipStream_t stream)
{
    const float* nf    = (const float*)d_in[0];
    const float* sc    = (const float*)d_in[1];
    const float* attrs = (const float*)d_in[2];
    const float *U3s[3], *U2s[3], *U1s[3], *W3s[3], *W2s[3], *W1s[3], *lins[3];
    for (int L = 0; L < 3; ++L) {
        const int o = 3 + 7 * L;
        U3s[L]  = (const float*)d_in[o + 0];
        U2s[L]  = (const float*)d_in[o + 1];
        U1s[L]  = (const float*)d_in[o + 2];
        W3s[L]  = (const float*)d_in[o + 3];
        W2s[L]  = (const float*)d_in[o + 4];
        W1s[L]  = (const float*)d_in[o + 5];
        lins[L] = (const float*)d_in[o + 6];
    }

    float* wsf   = (float*)d_ws;
    int* counts  = (int*)d_ws;
    int* cursor  = counts + 16;
    int* list    = counts + 48;
    float* T3ws = wsf + 4160;
    float* T2ws = T3ws + 8398080;
    float* T1ws = T2ws + 933120;
    float* pre  = T1ws + 103680;
    float* xg   = pre + 4718592;

    hipMemsetAsync(d_ws, 0, 128, stream);   // counts + cursor
    k_count  <<<16, 256, 0, stream>>>(attrs, counts);
    k_scatter<<<16, 256, 0, stream>>>(attrs, counts, cursor, list);
    k_gp<<<6622, 256, 0, stream>>>(nf, list,
                                   U3s[0], U3s[1], U3s[2], W3s[0], W3s[1], W3s[2],
                                   U2s[0], U2s[1], U2s[2], W2s[0], W2s[1], W2s[2],
                                   U1s[0], U1s[1], U1s[2], W1s[0], W1s[1], W1s[2],
                                   xg, T3ws, T2ws, T1ws);
    k_main<<<dim3(128, 10, 6), 64, 0, stream>>>(xg, counts, T3ws, T2ws, T1ws, pre);
    k_mixout<<<dim3(64, 9), 256, 0, stream>>>(pre, list, sc, lins[0], lins[1], lins[2], (float*)d_out);
}